// Round 5
// baseline (126.459 us; speedup 1.0000x reference)
//
#include <hip/hip_runtime.h>

// WaveletLayer on [4096,4096] fp32:
//   out = diag_s * DWT3( diag_g * (DWT3(diag_b * x))[perm] )
// Haar DWT3 packet layout: [cA3(512) | cD3(512) | cD2(1024) | cD1(2048)].
//
// History:
//  v1: 16-cols/thread, registered tables, dbuf LDS, R=4. 44 us, 26% occ.
//  v2: LDS-only barrier + prefetch -> regressed.
//  v3: launch_bounds(256,8) with registered tables -> VGPR=32 spill, 90 us.
//  v4: natural regs -> VGPR=68, 4-wave bucket again, 44 us.
//  v5: fully coalesced chunk layout (4x4 cols/thread, shfl_xor for L3) ->
//      ~41 us. Small win; still 4-wave bucket (tables pin VGPR>=68).
//  v6 (this round): the 58 persistent table registers (db/dg/pidx/diag_s)
//      are what keep VGPR above the 64-VGPR occupancy cliff (m69: waves/SIMD
//      halve at 64/128/256). Tables are L2-resident (80 KB << 4 MB/XCD), so:
//      load them per use instead of registering; prefetch only pidx across
//      the barrier (gather critical path). R=1, grid=4096, ONE barrier per
//      block, no buffer-reuse barrier. launch_bounds(256,8) pins the
//      allocator under 64 VGPR (live set ~40 now -- no spill risk, unlike
//      v3 whose required set exceeded the cap). 8 blocks/CU resident.

#define D   4096
#define NT  256            // 4 chunks x 4 columns per thread

#define C_INV_SQRT2 0.70710678118654752440f

typedef float vf2 __attribute__((ext_vector_type(2)));
typedef float vf4 __attribute__((ext_vector_type(4)));

// One Haar chunk: 4 contiguous columns -> d1 pair, d2, and level-3 value
// (even lane: cA3, odd lane: cD3) via cross-lane pairing of a2.
static __device__ __forceinline__ void haar_chunk(
    float v0, float v1, float v2, float v3, int odd,
    float& d1a, float& d1b, float& d2v, float& l3)
{
    float a10 = (v0 + v1) * C_INV_SQRT2;
    d1a       = (v0 - v1) * C_INV_SQRT2;
    float a11 = (v2 + v3) * C_INV_SQRT2;
    d1b       = (v2 - v3) * C_INV_SQRT2;
    float a2  = (a10 + a11) * C_INV_SQRT2;
    d2v       = (a10 - a11) * C_INV_SQRT2;
    float a2p = __shfl_xor(a2, 1);              // neighbor's a2 (lane t^1)
    // even lane holds a2[2m], partner a2[2m+1]:  a3 = (a2 + a2p)*c
    // odd  lane holds a2[2m+1], partner a2[2m]:  d3 = (a2p - a2)*c
    l3 = (odd ? (a2p - a2) : (a2 + a2p)) * C_INV_SQRT2;
}

__global__ __launch_bounds__(NT, 8) void wavelet_rows_kernel(
    const float* __restrict__ x,
    const float* __restrict__ diag_s,
    const float* __restrict__ diag_g,
    const float* __restrict__ diag_b,
    const int*   __restrict__ perm,
    float*       __restrict__ out)
{
    __shared__ float buf[D];          // single packet buffer: 16 KB/block

    const int t   = threadIdx.x;
    const int s   = t >> 1;           // lane-pair index
    const int odd = t & 1;
    const size_t row = (size_t)blockIdx.x;

    const vf4*  b4 = (const vf4*)diag_b;
    const vf4*  g4 = (const vf4*)diag_g;
    const int4* p4 = (const int4*)perm;
    const vf2*  s2 = (const vf2*)diag_s;

    // ---- phase A: load row (coalesced), DWT #1, scatter packet to LDS ----
    const vf4* x4 = (const vf4*)(x + row * (size_t)D);
    #pragma unroll
    for (int k = 0; k < 4; ++k) {
        vf4 xv = x4[256 * k + t];                      // HBM, 16B/lane coalesced
        vf4 bv = b4[256 * k + t];                      // L2-hot
        float d1a, d1b, d2v, l3;
        haar_chunk(xv.x * bv.x, xv.y * bv.y,
                   xv.z * bv.z, xv.w * bv.w, odd,
                   d1a, d1b, d2v, l3);
        vf2 dp; dp.x = d1a; dp.y = d1b;
        *(vf2*)&buf[2048 + 512 * k + 2 * t] = dp;      // cD1 pair
        buf[1024 + 256 * k + t] = d2v;                 // cD2
        buf[(odd ? 512 : 0) + 128 * k + s] = l3;       // cA3 | cD3
    }

    // prefetch permutation indices for phase B: the L2 latency of these
    // loads overlaps the barrier wait (they're the gather critical path).
    int4 pidx[4];
    #pragma unroll
    for (int k = 0; k < 4; ++k) pidx[k] = p4[256 * k + t];

    __syncthreads();

    // ---- phase B: gather * diag_g, DWT #2, * diag_s, NT store ----
    float* orow = out + row * (size_t)D;
    #pragma unroll
    for (int k = 0; k < 4; ++k) {
        // per-chunk table loads (L2-hot); latency hides under the ds_reads
        vf4  gv  = g4[256 * k + t];
        vf2  s1  = s2[1024 + 256 * k + t];             // cD1 scale pair
        float sv2 = diag_s[1024 + 256 * k + t];        // cD2 scale
        float sv3 = diag_s[(odd ? 512 : 0) + 128 * k + s];  // cA3|cD3 scale

        float w0 = buf[pidx[k].x] * gv.x;
        float w1 = buf[pidx[k].y] * gv.y;
        float w2 = buf[pidx[k].z] * gv.z;
        float w3 = buf[pidx[k].w] * gv.w;
        float e1a, e1b, e2v, f3;
        haar_chunk(w0, w1, w2, w3, odd, e1a, e1b, e2v, f3);

        vf2 ep; ep.x = e1a * s1.x; ep.y = e1b * s1.y;
        __builtin_nontemporal_store(ep, &((vf2*)orow)[1024 + 256 * k + t]);
        __builtin_nontemporal_store(e2v * sv2, &orow[1024 + 256 * k + t]);
        __builtin_nontemporal_store(f3 * sv3,
                                    &orow[(odd ? 512 : 0) + 128 * k + s]);
    }
}

extern "C" void kernel_launch(void* const* d_in, const int* in_sizes, int n_in,
                              void* d_out, int out_size, void* d_ws, size_t ws_size,
                              hipStream_t stream) {
    // setup_inputs() order: x, diag_s, diag_g, diag_b, dec_lo, dec_hi, perm, scales
    const float* x      = (const float*)d_in[0];
    const float* diag_s = (const float*)d_in[1];
    const float* diag_g = (const float*)d_in[2];
    const float* diag_b = (const float*)d_in[3];
    const int* perm     = (const int*)d_in[6];
    float* out          = (float*)d_out;

    wavelet_rows_kernel<<<4096, NT, 0, stream>>>(x, diag_s, diag_g, diag_b, perm, out);
}